// Round 5
// baseline (583.640 us; speedup 1.0000x reference)
//
#include <hip/hip_runtime.h>
#include <hip/hip_bf16.h>

// Problem constants (fixed by the reference)
#define BDIM 2
#define SEQ  2048
#define HID  1024
#define NH   16
#define HD   64
#define MROWS (BDIM * SEQ)   // 4096
#define QKVN  (3 * HID)      // 3072

typedef __attribute__((ext_vector_type(8))) short s8b;   // 8 bf16 (4 VGPRs)
typedef __attribute__((ext_vector_type(4))) float f4;    // MFMA C/D

__device__ __forceinline__ unsigned f2bf(float f) {
    unsigned u = __builtin_bit_cast(unsigned, f);
    return (u + 0x7FFFu + ((u >> 16) & 1u)) >> 16;   // round-to-nearest-even
}
__device__ __forceinline__ float bf2f(unsigned h) {
    return __builtin_bit_cast(float, h << 16);
}

// ---------------------------------------------------------------------------
// Prologue: split fp32 tensor into hi/lo bf16 planes. hi = bf16(x) RNE,
// lo = bf16(x - hi)  (x - hi is exact in fp32). 8 elems / thread.
// ---------------------------------------------------------------------------
__global__ __launch_bounds__(256) void split_hi_lo(
    const float* __restrict__ src, unsigned short* __restrict__ hi,
    unsigned short* __restrict__ lo, int n8)
{
    const int i = blockIdx.x * 256 + threadIdx.x;
    if (i >= n8) return;
    const float4* s = (const float4*)src + 2 * (size_t)i;
    float4 a = s[0], b = s[1];
    const float v[8] = {a.x, a.y, a.z, a.w, b.x, b.y, b.z, b.w};
    unsigned hu[8], lu[8];
#pragma unroll
    for (int j = 0; j < 8; ++j) {
        hu[j] = f2bf(v[j]);
        lu[j] = f2bf(v[j] - bf2f(hu[j]));
    }
    uint4 hv = {hu[0] | (hu[1] << 16), hu[2] | (hu[3] << 16),
                hu[4] | (hu[5] << 16), hu[6] | (hu[7] << 16)};
    uint4 lv = {lu[0] | (lu[1] << 16), lu[2] | (lu[3] << 16),
                lu[4] | (lu[5] << 16), lu[6] | (lu[7] << 16)};
    *((uint4*)hi + i) = hv;
    *((uint4*)lo + i) = lv;
}

// ---------------------------------------------------------------------------
// Split-bf16 MFMA GEMM: C[m][n] = sum_k A[m][k]*W[n][k] + bias[n], where
// A ~ Ah+Al, W ~ Wh+Wl (bf16 planes). 3 MFMA passes (hh, hl, lh); lo*lo
// dropped (~1e-5 rel). 128x128 tile, BK=32, 4 waves as 2x2 of 64x64.
// LDS rows padded to 80 B (start banks 20r%32: fragment reads/writes are
// <=2-way which is free per m136).
//
// __launch_bounds__(256, 2): round-4 post-mortem — without the min-waves arg
// the allocator picked an 80-VGPR budget and SPILLED the cross-barrier
// prefetch g[8] (128 B/thread/iter -> 805 MB of scratch writes/dispatch,
// measured WRITE_SIZE 758 MB; kernel ran at scratch-traffic speed).
// 2 waves/EU -> 256-reg budget -> ~214-reg live set fits, zero spill;
// LDS (40 KB) allows the same 2 blocks/CU anyway.
// ---------------------------------------------------------------------------
template <int OUTBF>
__global__ __launch_bounds__(256, 2) void gemm_split(
    const unsigned short* __restrict__ Ah, const unsigned short* __restrict__ Al,
    const unsigned short* __restrict__ Wh, const unsigned short* __restrict__ Wl,
    const float* __restrict__ bias, void* __restrict__ Cout, int N, int K)
{
    const int t   = threadIdx.x;
    const int l15 = t & 15;
    const int lg  = (t >> 4) & 3;
    const int w   = t >> 6;
    const int wr  = w >> 1, wc = w & 1;
    const int bm  = blockIdx.y * 128, bn = blockIdx.x * 128;

    __shared__ unsigned short AhS[128 * 40];
    __shared__ unsigned short AlS[128 * 40];
    __shared__ unsigned short WhS[128 * 40];
    __shared__ unsigned short WlS[128 * 40];

    f4 acc[4][4];
#pragma unroll
    for (int i = 0; i < 4; ++i)
#pragma unroll
        for (int j = 0; j < 4; ++j) acc[i][j] = (f4){0.f, 0.f, 0.f, 0.f};

    // staging map: thread t loads granule (row=t>>2, col8=(t&3)*8) and the
    // same at row+64, for each of the 4 planes (16 B each).
    const int sr = t >> 2;
    const int sc = (t & 3) * 8;
    const size_t aoff0 = (size_t)(bm + sr) * K + sc;
    const size_t aoff1 = (size_t)(bm + 64 + sr) * K + sc;
    const size_t woff0 = (size_t)(bn + sr) * K + sc;
    const size_t woff1 = (size_t)(bn + 64 + sr) * K + sc;
    const int dsb0 = sr * 80 + sc * 2;
    const int dsb1 = (64 + sr) * 80 + sc * 2;

    uint4 g[8];
#define LOADK(k0)                                                     \
    do {                                                              \
        g[0] = *(const uint4*)(Ah + aoff0 + (k0));                    \
        g[1] = *(const uint4*)(Ah + aoff1 + (k0));                    \
        g[2] = *(const uint4*)(Al + aoff0 + (k0));                    \
        g[3] = *(const uint4*)(Al + aoff1 + (k0));                    \
        g[4] = *(const uint4*)(Wh + woff0 + (k0));                    \
        g[5] = *(const uint4*)(Wh + woff1 + (k0));                    \
        g[6] = *(const uint4*)(Wl + woff0 + (k0));                    \
        g[7] = *(const uint4*)(Wl + woff1 + (k0));                    \
    } while (0)

    LOADK(0);
    for (int k0 = 0; k0 < K; k0 += 32) {
        __syncthreads();   // previous iteration's fragment reads done
        *(uint4*)((char*)AhS + dsb0) = g[0];
        *(uint4*)((char*)AhS + dsb1) = g[1];
        *(uint4*)((char*)AlS + dsb0) = g[2];
        *(uint4*)((char*)AlS + dsb1) = g[3];
        *(uint4*)((char*)WhS + dsb0) = g[4];
        *(uint4*)((char*)WhS + dsb1) = g[5];
        *(uint4*)((char*)WlS + dsb0) = g[6];
        *(uint4*)((char*)WlS + dsb1) = g[7];
        __syncthreads();
        if (k0 + 32 < K) LOADK(k0 + 32);   // issue early; MFMA phase hides HBM

        s8b bh[4], bl[4];
#pragma unroll
        for (int nt = 0; nt < 4; ++nt) {
            const int rb = (wc * 64 + nt * 16 + l15) * 80 + lg * 16;
            bh[nt] = *(const s8b*)((const char*)WhS + rb);
            bl[nt] = *(const s8b*)((const char*)WlS + rb);
        }
#pragma unroll
        for (int mt = 0; mt < 4; ++mt) {
            const int rb = (wr * 64 + mt * 16 + l15) * 80 + lg * 16;
            s8b ah = *(const s8b*)((const char*)AhS + rb);
            s8b al = *(const s8b*)((const char*)AlS + rb);
#pragma unroll
            for (int nt = 0; nt < 4; ++nt) {
                acc[mt][nt] = __builtin_amdgcn_mfma_f32_16x16x32_bf16(ah, bh[nt], acc[mt][nt], 0, 0, 0);
                acc[mt][nt] = __builtin_amdgcn_mfma_f32_16x16x32_bf16(ah, bl[nt], acc[mt][nt], 0, 0, 0);
                acc[mt][nt] = __builtin_amdgcn_mfma_f32_16x16x32_bf16(al, bh[nt], acc[mt][nt], 0, 0, 0);
            }
        }
    }
#undef LOADK

    float bv[4];
#pragma unroll
    for (int nt = 0; nt < 4; ++nt) bv[nt] = bias[bn + wc * 64 + nt * 16 + l15];

#pragma unroll
    for (int mt = 0; mt < 4; ++mt)
#pragma unroll
        for (int i = 0; i < 4; ++i) {
            const int m = bm + wr * 64 + mt * 16 + lg * 4 + i;
#pragma unroll
            for (int nt = 0; nt < 4; ++nt) {
                const int n = bn + wc * 64 + nt * 16 + l15;
                const float v = acc[mt][nt][i] + bv[nt];
                if (OUTBF)
                    ((unsigned short*)Cout)[(size_t)m * N + n] = (unsigned short)f2bf(v);
                else
                    ((float*)Cout)[(size_t)m * N + n] = v;
            }
        }
}

// ---------------------------------------------------------------------------
// XOR swizzle on 16B granules within a 128B row (attention LDS tiles).
// ---------------------------------------------------------------------------
__device__ __forceinline__ int sw_off(int row, int colbyte) {
    return row * 128 + (colbyte ^ ((((row & 7) ^ (row >> 3)) & 7) << 4));
}

// ---------------------------------------------------------------------------
// Flash attention, bf16-MFMA, bf16 qkv input ([B,S,3072], per-head
// interleaved: head h = cols [h*192, h*192+192) as Q|K|V of 64 each).
// One block = (b, h, 64 q-rows); 4 waves, wave w owns rows [w*16, w*16+16).
// 1/sqrt(64) folded into scores post-MFMA. Output: hi/lo bf16 planes for
// the split O-projection.
// ---------------------------------------------------------------------------
__global__ __launch_bounds__(256) void attn_fwd_mfma(
    const unsigned short* __restrict__ qkv,
    unsigned short* __restrict__ att_hi, unsigned short* __restrict__ att_lo)
{
    const int t   = threadIdx.x;
    const int w   = t >> 6;
    const int l   = t & 63;
    const int l15 = l & 15;
    const int lg  = l >> 4;

    const int bh = blockIdx.y;
    const int b  = bh >> 4;
    const int h  = bh & 15;
    const int q0 = blockIdx.x * 64;

    __shared__ unsigned short Ks[64 * 64];  // [key][d], swizzled
    __shared__ unsigned short Vt[64 * 64];  // [d][key], swizzled
    __shared__ unsigned short Ps[64 * 64];  // [q][key], swizzled, wave-private rows

    const unsigned short* base = qkv + (size_t)b * SEQ * QKVN + h * (3 * HD);

    // Q fragments: direct bf16 loads (no conversion, no pre-scale)
    s8b qf[2];
    {
        const unsigned short* qrow = base + (size_t)(q0 + w * 16 + l15) * QKVN;
        qf[0] = *(const s8b*)(qrow + lg * 8);
        qf[1] = *(const s8b*)(qrow + 32 + lg * 8);
    }

    float m_run[4], l_run[4];
    f4 oacc[4];
#pragma unroll
    for (int i = 0; i < 4; ++i) {
        m_run[i] = -1e30f;
        l_run[i] = 0.f;
        oacc[i]  = (f4){0.f, 0.f, 0.f, 0.f};
    }

    for (int kt = 0; kt < SEQ; kt += 64) {
        __syncthreads();   // previous tile's K/V reads complete

        // ---- stage K (16B copies) and V (transposed scatter), pure moves ----
#pragma unroll
        for (int rep = 0; rep < 2; ++rep) {
            const int idx = t + rep * 256;
            const int row = idx >> 3;   // key position within tile
            const int gg  = idx & 7;    // 8-elem granule
            const unsigned short* src = base + (size_t)(kt + row) * QKVN + HD + gg * 8;
            uint4 kg = *(const uint4*)src;
            *(uint4*)((char*)Ks + sw_off(row, gg * 16)) = kg;

            s8b v8 = *(const s8b*)(src + HD);
#pragma unroll
            for (int j = 0; j < 8; ++j)
                *(unsigned short*)((char*)Vt + sw_off(gg * 8 + j, row * 2)) =
                    (unsigned short)v8[j];
        }
        __syncthreads();

        // ---- QK^T: S[16 q][64 key] per wave ----
        f4 sacc[4];
#pragma unroll
        for (int nt = 0; nt < 4; ++nt) sacc[nt] = (f4){0.f, 0.f, 0.f, 0.f};
#pragma unroll
        for (int kc = 0; kc < 2; ++kc) {
            const int colb = kc * 64 + lg * 16;
#pragma unroll
            for (int nt = 0; nt < 4; ++nt) {
                s8b kf = *(const s8b*)((const char*)Ks + sw_off(nt * 16 + l15, colb));
                sacc[nt] = __builtin_amdgcn_mfma_f32_16x16x32_bf16(qf[kc], kf, sacc[nt], 0, 0, 0);
            }
        }
        // fold 1/sqrt(HD)
#pragma unroll
        for (int nt = 0; nt < 4; ++nt)
#pragma unroll
            for (int i = 0; i < 4; ++i) sacc[nt][i] *= 0.125f;

        // ---- online softmax ----
        float mt4[4];
#pragma unroll
        for (int i = 0; i < 4; ++i)
            mt4[i] = fmaxf(fmaxf(sacc[0][i], sacc[1][i]), fmaxf(sacc[2][i], sacc[3][i]));
#pragma unroll
        for (int s = 1; s <= 8; s <<= 1)
#pragma unroll
            for (int i = 0; i < 4; ++i)
                mt4[i] = fmaxf(mt4[i], __shfl_xor(mt4[i], s));

        float corr[4], rs[4];
#pragma unroll
        for (int i = 0; i < 4; ++i) {
            const float mn = fmaxf(m_run[i], mt4[i]);
            corr[i]  = __expf(m_run[i] - mn);
            m_run[i] = mn;
            rs[i]    = 0.f;
        }

        const int rowbase = w * 16 + lg * 4;
#pragma unroll
        for (int nt = 0; nt < 4; ++nt) {
#pragma unroll
            for (int i = 0; i < 4; ++i) {
                const float p = __expf(sacc[nt][i] - m_run[i]);
                rs[i] += p;
                *(unsigned short*)((char*)Ps + sw_off(rowbase + i, (nt * 16 + l15) * 2)) =
                    (unsigned short)f2bf(p);
            }
        }
#pragma unroll
        for (int s = 1; s <= 8; s <<= 1)
#pragma unroll
            for (int i = 0; i < 4; ++i)
                rs[i] += __shfl_xor(rs[i], s);
#pragma unroll
        for (int i = 0; i < 4; ++i)
            l_run[i] = l_run[i] * corr[i] + rs[i];
#pragma unroll
        for (int nt = 0; nt < 4; ++nt)
#pragma unroll
            for (int i = 0; i < 4; ++i)
                oacc[nt][i] *= corr[i];

        // ---- PV: O[16 q][64 d] += P @ V ----
#pragma unroll
        for (int kk = 0; kk < 2; ++kk) {
            const int colb = kk * 64 + lg * 16;
            s8b pf = *(const s8b*)((const char*)Ps + sw_off(w * 16 + l15, colb));
#pragma unroll
            for (int nt = 0; nt < 4; ++nt) {
                s8b vf = *(const s8b*)((const char*)Vt + sw_off(nt * 16 + l15, colb));
                oacc[nt] = __builtin_amdgcn_mfma_f32_16x16x32_bf16(pf, vf, oacc[nt], 0, 0, 0);
            }
        }
    }

    // ---- epilogue: normalize, split into hi/lo bf16 planes [B,S,HID] ----
    float inv[4];
#pragma unroll
    for (int i = 0; i < 4; ++i) inv[i] = 1.f / l_run[i];
#pragma unroll
    for (int i = 0; i < 4; ++i) {
        const size_t rowb = (size_t)(b * SEQ + q0 + w * 16 + lg * 4 + i) * HID + h * HD + l15;
#pragma unroll
        for (int nt = 0; nt < 4; ++nt) {
            const float v = oacc[nt][i] * inv[i];
            const unsigned hu = f2bf(v);
            const unsigned lu = f2bf(v - bf2f(hu));
            att_hi[rowb + nt * 16] = (unsigned short)hu;
            att_lo[rowb + nt * 16] = (unsigned short)lu;
        }
    }
}

// ---------------------------------------------------------------------------
// Workspace layout (56 MB total):
//   qkv_bf [4096][3072] bf16              24 MB
//   wh, wl [3072][1024] bf16          2 x  6 MB
//   owh, owl [1024][1024] bf16        2 x  2 MB
//   xh, xl [4096][1024] bf16          2 x  8 MB   (aliased by att_hi/att_lo
//                                                  after the QKV GEMM is done)
// ---------------------------------------------------------------------------
extern "C" void kernel_launch(void* const* d_in, const int* in_sizes, int n_in,
                              void* d_out, int out_size, void* d_ws, size_t ws_size,
                              hipStream_t stream) {
    const float* x     = (const float*)d_in[0];
    const float* qkv_w = (const float*)d_in[1];
    const float* qkv_b = (const float*)d_in[2];
    const float* o_w   = (const float*)d_in[3];
    const float* o_b   = (const float*)d_in[4];
    float* out = (float*)d_out;

    char* ws = (char*)d_ws;
    unsigned short* qkv_bf = (unsigned short*)ws;                      ws += (size_t)MROWS * QKVN * 2;
    unsigned short* wh     = (unsigned short*)ws;                      ws += (size_t)QKVN * HID * 2;
    unsigned short* wl     = (unsigned short*)ws;                      ws += (size_t)QKVN * HID * 2;
    unsigned short* owh    = (unsigned short*)ws;                      ws += (size_t)HID * HID * 2;
    unsigned short* owl    = (unsigned short*)ws;                      ws += (size_t)HID * HID * 2;
    unsigned short* xh     = (unsigned short*)ws;                      ws += (size_t)MROWS * HID * 2;
    unsigned short* xl     = (unsigned short*)ws;
    unsigned short* att_hi = xh;   // alias: x planes dead after QKV GEMM
    unsigned short* att_lo = xl;

    split_hi_lo<<<(MROWS * HID / 8) / 256, 256, 0, stream>>>(x, xh, xl, MROWS * HID / 8);
    split_hi_lo<<<(QKVN * HID / 8) / 256, 256, 0, stream>>>(qkv_w, wh, wl, QKVN * HID / 8);
    split_hi_lo<<<(HID * HID / 8) / 256, 256, 0, stream>>>(o_w, owh, owl, HID * HID / 8);

    gemm_split<1><<<dim3(QKVN / 128, MROWS / 128), 256, 0, stream>>>(
        xh, xl, wh, wl, qkv_b, qkv_bf, QKVN, HID);

    attn_fwd_mfma<<<dim3(SEQ / 64, BDIM * NH), 256, 0, stream>>>(qkv_bf, att_hi, att_lo);

    gemm_split<0><<<dim3(HID / 128, MROWS / 128), 256, 0, stream>>>(
        att_hi, att_lo, owh, owl, o_b, out, HID, HID);

    (void)in_sizes; (void)n_in; (void)out_size; (void)ws_size;
}

// Round 6
// 340.286 us; speedup vs baseline: 1.7151x; 1.7151x over previous
//
#include <hip/hip_runtime.h>
#include <hip/hip_bf16.h>

// Problem constants (fixed by the reference)
#define BDIM 2
#define SEQ  2048
#define HID  1024
#define NH   16
#define HD   64
#define MROWS (BDIM * SEQ)   // 4096
#define QKVN  (3 * HID)      // 3072

typedef __attribute__((ext_vector_type(8))) short s8b;   // 8 bf16 (4 VGPRs)
typedef __attribute__((ext_vector_type(4))) float f4;    // MFMA C/D

__device__ __forceinline__ unsigned f2bf(float f) {
    unsigned u = __builtin_bit_cast(unsigned, f);
    return (u + 0x7FFFu + ((u >> 16) & 1u)) >> 16;   // round-to-nearest-even
}
__device__ __forceinline__ float bf2f(unsigned h) {
    return __builtin_bit_cast(float, h << 16);
}

// ---------------------------------------------------------------------------
// Prologue: split fp32 tensor into hi/lo bf16 planes. hi = bf16(x) RNE,
// lo = bf16(x - hi)  (x - hi is exact in fp32). 8 elems / thread.
// ---------------------------------------------------------------------------
__global__ __launch_bounds__(256) void split_hi_lo(
    const float* __restrict__ src, unsigned short* __restrict__ hi,
    unsigned short* __restrict__ lo, int n8)
{
    const int i = blockIdx.x * 256 + threadIdx.x;
    if (i >= n8) return;
    const float4* s = (const float4*)src + 2 * (size_t)i;
    float4 a = s[0], b = s[1];
    const float v[8] = {a.x, a.y, a.z, a.w, b.x, b.y, b.z, b.w};
    unsigned hu[8], lu[8];
#pragma unroll
    for (int j = 0; j < 8; ++j) {
        hu[j] = f2bf(v[j]);
        lu[j] = f2bf(v[j] - bf2f(hu[j]));
    }
    uint4 hv = {hu[0] | (hu[1] << 16), hu[2] | (hu[3] << 16),
                hu[4] | (hu[5] << 16), hu[6] | (hu[7] << 16)};
    uint4 lv = {lu[0] | (lu[1] << 16), lu[2] | (lu[3] << 16),
                lu[4] | (lu[5] << 16), lu[6] | (lu[7] << 16)};
    *((uint4*)hi + i) = hv;
    *((uint4*)lo + i) = lv;
}

// ---------------------------------------------------------------------------
// Split-bf16 MFMA GEMM: C[m][n] = sum_k A[m][k]*W[n][k] + bias[n], where
// A ~ Ah+Al, W ~ Wh+Wl (bf16 planes). 3 MFMA passes (hh, hl, lh); lo*lo
// dropped (~1e-5 rel). 128x128 tile, BK=32, 4 waves as 2x2 of 64x64.
//
// Round-5 post-mortem: register prefetch g[8] was spilled every K-step
// (WRITE_SIZE 783 MB = 128 B/thread/iter; kernel ran at scratch-traffic
// speed, MfmaUtil 12%). launch_bounds(256,2) gives a waves/EU RANGE [2,8]
// and the RA still chased 7 waves/EU (72 VGPR) that LDS can never seat.
// Fix: NO register staging at all — global_load_lds direct HBM->LDS
// (nothing lives across a barrier but the accumulators), double-buffered,
// and amdgpu_waves_per_eu(2,2) pins the budget to 256 regs = the
// occupancy LDS allows anyway (2 blocks/CU at 64 KB).
//
// LDS layout per plane: [128 rows][4 granules of 16B] linear (gload_lds
// writes base+lane*16; rule #21: dest must be linear). Bank-conflict fix
// is XOR on BOTH sides: source granule j^(row&3) pre-applied to the
// global address, same XOR on the fragment ds_read -> <=2-way (free).
// ---------------------------------------------------------------------------
template <int OUTBF>
__global__ __launch_bounds__(256)
__attribute__((amdgpu_waves_per_eu(2, 2)))
void gemm_split(
    const unsigned short* __restrict__ Ah, const unsigned short* __restrict__ Al,
    const unsigned short* __restrict__ Wh, const unsigned short* __restrict__ Wl,
    const float* __restrict__ bias, void* __restrict__ Cout, int N, int K)
{
    const int t   = threadIdx.x;
    const int l   = t & 63;
    const int l15 = t & 15;
    const int lg  = (t >> 4) & 3;
    const int w   = t >> 6;
    const int wr  = w >> 1, wc = w & 1;
    const int bm  = blockIdx.y * 128, bn = blockIdx.x * 128;

    // [buf][plane][128*32]: planes 0=Ah 1=Al 2=Wh 3=Wl, 8 KB each
    __shared__ unsigned short SB[2][4][128 * 32];

    f4 acc[4][4];
#pragma unroll
    for (int i = 0; i < 4; ++i)
#pragma unroll
        for (int j = 0; j < 4; ++j) acc[i][j] = (f4){0.f, 0.f, 0.f, 0.f};

    // Each wave stages its own plane: 8 calls x 1 KB (16 rows each).
    const unsigned short* plane_src = (w == 0) ? Ah : (w == 1) ? Al
                                    : (w == 2) ? Wh : Wl;
    const int rb0 = (w < 2) ? bm : bn;
    const int gsw = ((l & 3) ^ ((l >> 2) & 3)) * 8;   // source granule XOR

    auto stage = [&](int buf, int k0) {
        const unsigned short* gp =
            plane_src + (size_t)(rb0 + (l >> 2)) * K + k0 + gsw;
        unsigned short* lb = &SB[buf][w][0];
#pragma unroll
        for (int c = 0; c < 8; ++c)
            __builtin_amdgcn_global_load_lds(
                (const __attribute__((address_space(1))) void*)(gp + (size_t)(c * 16) * K),
                (__attribute__((address_space(3))) void*)(lb + c * 512),
                16, 0, 0);
    };

    const int ksw = ((lg ^ (l15 & 3)) & 3) << 3;   // read-side XOR (elems)

    stage(0, 0);
    __syncthreads();   // drains vmcnt -> buf0 staged

    int cur = 0;
    const int nsteps = K >> 5;
    for (int step = 0; step < nsteps; ++step) {
        if (step + 1 < nsteps) stage(cur ^ 1, (step + 1) << 5);

        const unsigned short* base = &SB[cur][0][0];
        s8b bh[4], bl[4];
#pragma unroll
        for (int nt = 0; nt < 4; ++nt) {
            const int ro = (wc * 64 + nt * 16 + l15) * 32 + ksw;
            bh[nt] = *(const s8b*)(base + 2 * 4096 + ro);
            bl[nt] = *(const s8b*)(base + 3 * 4096 + ro);
        }
#pragma unroll
        for (int mt = 0; mt < 4; ++mt) {
            const int ro = (wr * 64 + mt * 16 + l15) * 32 + ksw;
            s8b ah = *(const s8b*)(base + ro);
            s8b al = *(const s8b*)(base + 4096 + ro);
#pragma unroll
            for (int nt = 0; nt < 4; ++nt) {
                acc[mt][nt] = __builtin_amdgcn_mfma_f32_16x16x32_bf16(ah, bh[nt], acc[mt][nt], 0, 0, 0);
                acc[mt][nt] = __builtin_amdgcn_mfma_f32_16x16x32_bf16(ah, bl[nt], acc[mt][nt], 0, 0, 0);
                acc[mt][nt] = __builtin_amdgcn_mfma_f32_16x16x32_bf16(al, bh[nt], acc[mt][nt], 0, 0, 0);
            }
        }
        __syncthreads();   // compute reads done + next-tile staging drained
        cur ^= 1;
    }

    float bv[4];
#pragma unroll
    for (int nt = 0; nt < 4; ++nt) bv[nt] = bias[bn + wc * 64 + nt * 16 + l15];

#pragma unroll
    for (int mt = 0; mt < 4; ++mt)
#pragma unroll
        for (int i = 0; i < 4; ++i) {
            const int m = bm + wr * 64 + mt * 16 + lg * 4 + i;
#pragma unroll
            for (int nt = 0; nt < 4; ++nt) {
                const int n = bn + wc * 64 + nt * 16 + l15;
                const float v = acc[mt][nt][i] + bv[nt];
                if (OUTBF)
                    ((unsigned short*)Cout)[(size_t)m * N + n] = (unsigned short)f2bf(v);
                else
                    ((float*)Cout)[(size_t)m * N + n] = v;
            }
        }
}

// ---------------------------------------------------------------------------
// XOR swizzle on 16B granules within a 128B row (attention LDS tiles).
// ---------------------------------------------------------------------------
__device__ __forceinline__ int sw_off(int row, int colbyte) {
    return row * 128 + (colbyte ^ ((((row & 7) ^ (row >> 3)) & 7) << 4));
}

// ---------------------------------------------------------------------------
// Flash attention, bf16-MFMA, bf16 qkv input ([B,S,3072], per-head
// interleaved: head h = cols [h*192, h*192+192) as Q|K|V of 64 each).
// One block = (b, h, 64 q-rows); 4 waves, wave w owns rows [w*16, w*16+16).
// 1/sqrt(64) folded into scores post-MFMA. Output: hi/lo bf16 planes for
// the split O-projection.
// ---------------------------------------------------------------------------
__global__ __launch_bounds__(256) void attn_fwd_mfma(
    const unsigned short* __restrict__ qkv,
    unsigned short* __restrict__ att_hi, unsigned short* __restrict__ att_lo)
{
    const int t   = threadIdx.x;
    const int w   = t >> 6;
    const int l   = t & 63;
    const int l15 = l & 15;
    const int lg  = l >> 4;

    const int bh = blockIdx.y;
    const int b  = bh >> 4;
    const int h  = bh & 15;
    const int q0 = blockIdx.x * 64;

    __shared__ unsigned short Ks[64 * 64];  // [key][d], swizzled
    __shared__ unsigned short Vt[64 * 64];  // [d][key], swizzled
    __shared__ unsigned short Ps[64 * 64];  // [q][key], swizzled, wave-private rows

    const unsigned short* base = qkv + (size_t)b * SEQ * QKVN + h * (3 * HD);

    // Q fragments: direct bf16 loads (no conversion, no pre-scale)
    s8b qf[2];
    {
        const unsigned short* qrow = base + (size_t)(q0 + w * 16 + l15) * QKVN;
        qf[0] = *(const s8b*)(qrow + lg * 8);
        qf[1] = *(const s8b*)(qrow + 32 + lg * 8);
    }

    float m_run[4], l_run[4];
    f4 oacc[4];
#pragma unroll
    for (int i = 0; i < 4; ++i) {
        m_run[i] = -1e30f;
        l_run[i] = 0.f;
        oacc[i]  = (f4){0.f, 0.f, 0.f, 0.f};
    }

    for (int kt = 0; kt < SEQ; kt += 64) {
        __syncthreads();   // previous tile's K/V reads complete

        // ---- stage K (16B copies) and V (transposed scatter), pure moves ----
#pragma unroll
        for (int rep = 0; rep < 2; ++rep) {
            const int idx = t + rep * 256;
            const int row = idx >> 3;   // key position within tile
            const int gg  = idx & 7;    // 8-elem granule
            const unsigned short* src = base + (size_t)(kt + row) * QKVN + HD + gg * 8;
            uint4 kg = *(const uint4*)src;
            *(uint4*)((char*)Ks + sw_off(row, gg * 16)) = kg;

            s8b v8 = *(const s8b*)(src + HD);
#pragma unroll
            for (int j = 0; j < 8; ++j)
                *(unsigned short*)((char*)Vt + sw_off(gg * 8 + j, row * 2)) =
                    (unsigned short)v8[j];
        }
        __syncthreads();

        // ---- QK^T: S[16 q][64 key] per wave ----
        f4 sacc[4];
#pragma unroll
        for (int nt = 0; nt < 4; ++nt) sacc[nt] = (f4){0.f, 0.f, 0.f, 0.f};
#pragma unroll
        for (int kc = 0; kc < 2; ++kc) {
            const int colb = kc * 64 + lg * 16;
#pragma unroll
            for (int nt = 0; nt < 4; ++nt) {
                s8b kf = *(const s8b*)((const char*)Ks + sw_off(nt * 16 + l15, colb));
                sacc[nt] = __builtin_amdgcn_mfma_f32_16x16x32_bf16(qf[kc], kf, sacc[nt], 0, 0, 0);
            }
        }
        // fold 1/sqrt(HD)
#pragma unroll
        for (int nt = 0; nt < 4; ++nt)
#pragma unroll
            for (int i = 0; i < 4; ++i) sacc[nt][i] *= 0.125f;

        // ---- online softmax ----
        float mt4[4];
#pragma unroll
        for (int i = 0; i < 4; ++i)
            mt4[i] = fmaxf(fmaxf(sacc[0][i], sacc[1][i]), fmaxf(sacc[2][i], sacc[3][i]));
#pragma unroll
        for (int s = 1; s <= 8; s <<= 1)
#pragma unroll
            for (int i = 0; i < 4; ++i)
                mt4[i] = fmaxf(mt4[i], __shfl_xor(mt4[i], s));

        float corr[4], rs[4];
#pragma unroll
        for (int i = 0; i < 4; ++i) {
            const float mn = fmaxf(m_run[i], mt4[i]);
            corr[i]  = __expf(m_run[i] - mn);
            m_run[i] = mn;
            rs[i]    = 0.f;
        }

        const int rowbase = w * 16 + lg * 4;
#pragma unroll
        for (int nt = 0; nt < 4; ++nt) {
#pragma unroll
            for (int i = 0; i < 4; ++i) {
                const float p = __expf(sacc[nt][i] - m_run[i]);
                rs[i] += p;
                *(unsigned short*)((char*)Ps + sw_off(rowbase + i, (nt * 16 + l15) * 2)) =
                    (unsigned short)f2bf(p);
            }
        }
#pragma unroll
        for (int s = 1; s <= 8; s <<= 1)
#pragma unroll
            for (int i = 0; i < 4; ++i)
                rs[i] += __shfl_xor(rs[i], s);
#pragma unroll
        for (int i = 0; i < 4; ++i)
            l_run[i] = l_run[i] * corr[i] + rs[i];
#pragma unroll
        for (int nt = 0; nt < 4; ++nt)
#pragma unroll
            for (int i = 0; i < 4; ++i)
                oacc[nt][i] *= corr[i];

        // ---- PV: O[16 q][64 d] += P @ V ----
#pragma unroll
        for (int kk = 0; kk < 2; ++kk) {
            const int colb = kk * 64 + lg * 16;
            s8b pf = *(const s8b*)((const char*)Ps + sw_off(w * 16 + l15, colb));
#pragma unroll
            for (int nt = 0; nt < 4; ++nt) {
                s8b vf = *(const s8b*)((const char*)Vt + sw_off(nt * 16 + l15, colb));
                oacc[nt] = __builtin_amdgcn_mfma_f32_16x16x32_bf16(pf, vf, oacc[nt], 0, 0, 0);
            }
        }
    }

    // ---- epilogue: normalize, split into hi/lo bf16 planes [B,S,HID] ----
    float inv[4];
#pragma unroll
    for (int i = 0; i < 4; ++i) inv[i] = 1.f / l_run[i];
#pragma unroll
    for (int i = 0; i < 4; ++i) {
        const size_t rowb = (size_t)(b * SEQ + q0 + w * 16 + lg * 4 + i) * HID + h * HD + l15;
#pragma unroll
        for (int nt = 0; nt < 4; ++nt) {
            const float v = oacc[nt][i] * inv[i];
            const unsigned hu = f2bf(v);
            const unsigned lu = f2bf(v - bf2f(hu));
            att_hi[rowb + nt * 16] = (unsigned short)hu;
            att_lo[rowb + nt * 16] = (unsigned short)lu;
        }
    }
}

// ---------------------------------------------------------------------------
// Workspace layout (56 MB total):
//   qkv_bf [4096][3072] bf16              24 MB
//   wh, wl [3072][1024] bf16          2 x  6 MB
//   owh, owl [1024][1024] bf16        2 x  2 MB
//   xh, xl [4096][1024] bf16          2 x  8 MB   (aliased by att_hi/att_lo
//                                                  after the QKV GEMM is done)
// ---------------------------------------------------------------------------
extern "C" void kernel_launch(void* const* d_in, const int* in_sizes, int n_in,
                              void* d_out, int out_size, void* d_ws, size_t ws_size,
                              hipStream_t stream) {
    const float* x     = (const float*)d_in[0];
    const float* qkv_w = (const float*)d_in[1];
    const float* qkv_b = (const float*)d_in[2];
    const float* o_w   = (const float*)d_in[3];
    const float* o_b   = (const float*)d_in[4];
    float* out = (float*)d_out;

    char* ws = (char*)d_ws;
    unsigned short* qkv_bf = (unsigned short*)ws;                      ws += (size_t)MROWS * QKVN * 2;
    unsigned short* wh     = (unsigned short*)ws;                      ws += (size_t)QKVN * HID * 2;
    unsigned short* wl     = (unsigned short*)ws;                      ws += (size_t)QKVN * HID * 2;
    unsigned short* owh    = (unsigned short*)ws;                      ws += (size_t)HID * HID * 2;
    unsigned short* owl    = (unsigned short*)ws;                      ws += (size_t)HID * HID * 2;
    unsigned short* xh     = (unsigned short*)ws;                      ws += (size_t)MROWS * HID * 2;
    unsigned short* xl     = (unsigned short*)ws;
    unsigned short* att_hi = xh;   // alias: x planes dead after QKV GEMM
    unsigned short* att_lo = xl;

    split_hi_lo<<<(MROWS * HID / 8) / 256, 256, 0, stream>>>(x, xh, xl, MROWS * HID / 8);
    split_hi_lo<<<(QKVN * HID / 8) / 256, 256, 0, stream>>>(qkv_w, wh, wl, QKVN * HID / 8);
    split_hi_lo<<<(HID * HID / 8) / 256, 256, 0, stream>>>(o_w, owh, owl, HID * HID / 8);

    gemm_split<1><<<dim3(QKVN / 128, MROWS / 128), 256, 0, stream>>>(
        xh, xl, wh, wl, qkv_b, qkv_bf, QKVN, HID);

    attn_fwd_mfma<<<dim3(SEQ / 64, BDIM * NH), 256, 0, stream>>>(qkv_bf, att_hi, att_lo);

    gemm_split<0><<<dim3(HID / 128, MROWS / 128), 256, 0, stream>>>(
        att_hi, att_lo, owh, owl, o_b, out, HID, HID);

    (void)in_sizes; (void)n_in; (void)out_size; (void)ws_size;
}

// Round 7
// 319.065 us; speedup vs baseline: 1.8292x; 1.0665x over previous
//
#include <hip/hip_runtime.h>
#include <hip/hip_bf16.h>

// Problem constants (fixed by the reference)
#define BDIM 2
#define SEQ  2048
#define HID  1024
#define NH   16
#define HD   64
#define MROWS (BDIM * SEQ)   // 4096
#define QKVN  (3 * HID)      // 3072
#define QBLK 128

typedef __attribute__((ext_vector_type(8))) short s8b;   // 8 bf16 (4 VGPRs)
typedef __attribute__((ext_vector_type(4))) float f4;    // MFMA C/D

__device__ __forceinline__ unsigned f2bf(float f) {
    unsigned u = __builtin_bit_cast(unsigned, f);
    return (u + 0x7FFFu + ((u >> 16) & 1u)) >> 16;   // round-to-nearest-even
}
__device__ __forceinline__ float bf2f(unsigned h) {
    return __builtin_bit_cast(float, h << 16);
}

// ---------------------------------------------------------------------------
// Prologue: split fp32 tensor into hi/lo bf16 planes.
// ---------------------------------------------------------------------------
__global__ __launch_bounds__(256) void split_hi_lo(
    const float* __restrict__ src, unsigned short* __restrict__ hi,
    unsigned short* __restrict__ lo, int n8)
{
    const int i = blockIdx.x * 256 + threadIdx.x;
    if (i >= n8) return;
    const float4* s = (const float4*)src + 2 * (size_t)i;
    float4 a = s[0], b = s[1];
    const float v[8] = {a.x, a.y, a.z, a.w, b.x, b.y, b.z, b.w};
    unsigned hu[8], lu[8];
#pragma unroll
    for (int j = 0; j < 8; ++j) {
        hu[j] = f2bf(v[j]);
        lu[j] = f2bf(v[j] - bf2f(hu[j]));
    }
    uint4 hv = {hu[0] | (hu[1] << 16), hu[2] | (hu[3] << 16),
                hu[4] | (hu[5] << 16), hu[6] | (hu[7] << 16)};
    uint4 lv = {lu[0] | (lu[1] << 16), lu[2] | (lu[3] << 16),
                lu[4] | (lu[5] << 16), lu[6] | (lu[7] << 16)};
    *((uint4*)hi + i) = hv;
    *((uint4*)lo + i) = lv;
}

// ---------------------------------------------------------------------------
// Split-bf16 MFMA GEMM (unchanged from round 6 — verified good).
// global_load_lds direct staging, double-buffered, no register prefetch.
// ---------------------------------------------------------------------------
template <int OUTBF>
__global__ __launch_bounds__(256)
__attribute__((amdgpu_waves_per_eu(2, 2)))
void gemm_split(
    const unsigned short* __restrict__ Ah, const unsigned short* __restrict__ Al,
    const unsigned short* __restrict__ Wh, const unsigned short* __restrict__ Wl,
    const float* __restrict__ bias, void* __restrict__ Cout, int N, int K)
{
    const int t   = threadIdx.x;
    const int l   = t & 63;
    const int l15 = t & 15;
    const int lg  = (t >> 4) & 3;
    const int w   = t >> 6;
    const int wr  = w >> 1, wc = w & 1;
    const int bm  = blockIdx.y * 128, bn = blockIdx.x * 128;

    __shared__ unsigned short SB[2][4][128 * 32];

    f4 acc[4][4];
#pragma unroll
    for (int i = 0; i < 4; ++i)
#pragma unroll
        for (int j = 0; j < 4; ++j) acc[i][j] = (f4){0.f, 0.f, 0.f, 0.f};

    const unsigned short* plane_src = (w == 0) ? Ah : (w == 1) ? Al
                                    : (w == 2) ? Wh : Wl;
    const int rb0 = (w < 2) ? bm : bn;
    const int gsw = ((l & 3) ^ ((l >> 2) & 3)) * 8;

    auto stage = [&](int buf, int k0) {
        const unsigned short* gp =
            plane_src + (size_t)(rb0 + (l >> 2)) * K + k0 + gsw;
        unsigned short* lb = &SB[buf][w][0];
#pragma unroll
        for (int c = 0; c < 8; ++c)
            __builtin_amdgcn_global_load_lds(
                (const __attribute__((address_space(1))) void*)(gp + (size_t)(c * 16) * K),
                (__attribute__((address_space(3))) void*)(lb + c * 512),
                16, 0, 0);
    };

    const int ksw = ((lg ^ (l15 & 3)) & 3) << 3;

    stage(0, 0);
    __syncthreads();

    int cur = 0;
    const int nsteps = K >> 5;
    for (int step = 0; step < nsteps; ++step) {
        if (step + 1 < nsteps) stage(cur ^ 1, (step + 1) << 5);

        const unsigned short* base = &SB[cur][0][0];
        s8b bh[4], bl[4];
#pragma unroll
        for (int nt = 0; nt < 4; ++nt) {
            const int ro = (wc * 64 + nt * 16 + l15) * 32 + ksw;
            bh[nt] = *(const s8b*)(base + 2 * 4096 + ro);
            bl[nt] = *(const s8b*)(base + 3 * 4096 + ro);
        }
#pragma unroll
        for (int mt = 0; mt < 4; ++mt) {
            const int ro = (wr * 64 + mt * 16 + l15) * 32 + ksw;
            s8b ah = *(const s8b*)(base + ro);
            s8b al = *(const s8b*)(base + 4096 + ro);
#pragma unroll
            for (int nt = 0; nt < 4; ++nt) {
                acc[mt][nt] = __builtin_amdgcn_mfma_f32_16x16x32_bf16(ah, bh[nt], acc[mt][nt], 0, 0, 0);
                acc[mt][nt] = __builtin_amdgcn_mfma_f32_16x16x32_bf16(ah, bl[nt], acc[mt][nt], 0, 0, 0);
                acc[mt][nt] = __builtin_amdgcn_mfma_f32_16x16x32_bf16(al, bh[nt], acc[mt][nt], 0, 0, 0);
            }
        }
        __syncthreads();
        cur ^= 1;
    }

    float bv[4];
#pragma unroll
    for (int nt = 0; nt < 4; ++nt) bv[nt] = bias[bn + wc * 64 + nt * 16 + l15];

#pragma unroll
    for (int mt = 0; mt < 4; ++mt)
#pragma unroll
        for (int i = 0; i < 4; ++i) {
            const int m = bm + wr * 64 + mt * 16 + lg * 4 + i;
#pragma unroll
            for (int nt = 0; nt < 4; ++nt) {
                const int n = bn + wc * 64 + nt * 16 + l15;
                const float v = acc[mt][nt][i] + bv[nt];
                if (OUTBF)
                    ((unsigned short*)Cout)[(size_t)m * N + n] = (unsigned short)f2bf(v);
                else
                    ((float*)Cout)[(size_t)m * N + n] = v;
            }
        }
}

// ---------------------------------------------------------------------------
// XOR swizzle on 16B granules within a 128B row (LDS tiles).
// ---------------------------------------------------------------------------
__device__ __forceinline__ int sw_off(int row, int colbyte) {
    return row * 128 + (colbyte ^ ((((row & 7) ^ (row >> 3)) & 7) << 4));
}

// ---------------------------------------------------------------------------
// One-shot V pre-transpose: vt[bh][d][s] = qkv_bf[b][s][h*192 + 128 + d].
// LDS-tiled 64x64 (swizzled); vector loads + vector stores, scalar LDS
// gathers in between (done ONCE instead of per attention block).
// ---------------------------------------------------------------------------
__global__ __launch_bounds__(256) void transpose_v(
    const unsigned short* __restrict__ qkv, unsigned short* __restrict__ vt)
{
    const int bh = blockIdx.y;
    const int b  = bh >> 4, h = bh & 15;
    const int s0 = blockIdx.x * 64;
    const int t  = threadIdx.x;

    __shared__ unsigned short T[64 * 64];  // [s][d] swizzled

#pragma unroll
    for (int rep = 0; rep < 2; ++rep) {
        const int idx = t + rep * 256;
        const int srow = idx >> 3, gg = idx & 7;
        uint4 v = *(const uint4*)(qkv + (size_t)(b * SEQ + s0 + srow) * QKVN
                                  + h * (3 * HD) + 2 * HD + gg * 8);
        *(uint4*)((char*)T + sw_off(srow, gg * 16)) = v;
    }
    __syncthreads();
#pragma unroll
    for (int rep = 0; rep < 2; ++rep) {
        const int idx = t + rep * 256;
        const int drow = idx >> 3, gg = idx & 7;
        unsigned short tmp[8];
#pragma unroll
        for (int j = 0; j < 8; ++j)
            tmp[j] = *(const unsigned short*)((const char*)T + sw_off(gg * 8 + j, drow * 2));
        *(uint4*)(vt + ((size_t)bh * 64 + drow) * SEQ + s0 + gg * 8) = *(const uint4*)tmp;
    }
}

// ---------------------------------------------------------------------------
// Flash attention, bf16 MFMA. One block = (b, h, 128 q-rows); 8 waves,
// wave w owns q-rows [w*16, w*16+16). 64-key tiles.
// K staged from qkv (vectorized), V staged from pre-transposed vt
// (vectorized — no scatter). Softmax in exp2 domain (0.125*log2e folded
// into scores). T13-lite: skip O-rescale when no row-max grew.
// ---------------------------------------------------------------------------
__global__ __launch_bounds__(512) void attn_fwd_mfma(
    const unsigned short* __restrict__ qkv,
    const unsigned short* __restrict__ vt,
    unsigned short* __restrict__ att_hi, unsigned short* __restrict__ att_lo)
{
    const int t   = threadIdx.x;
    const int w   = t >> 6;     // 0..7
    const int l   = t & 63;
    const int l15 = l & 15;
    const int lg  = l >> 4;

    const int bh = blockIdx.y;
    const int b  = bh >> 4;
    const int h  = bh & 15;
    const int q0 = blockIdx.x * QBLK;

    __shared__ unsigned short Ks[64 * 64];     // [key][d], swizzled
    __shared__ unsigned short Vt[64 * 64];     // [d][key], swizzled
    __shared__ unsigned short Ps[QBLK * 64];   // [q][key], swizzled, wave-private rows

    const unsigned short* base  = qkv + (size_t)b * SEQ * QKVN + h * (3 * HD);
    const unsigned short* vbase = vt + (size_t)bh * 64 * SEQ;

    // Q fragments in registers
    s8b qf[2];
    {
        const unsigned short* qrow = base + (size_t)(q0 + w * 16 + l15) * QKVN;
        qf[0] = *(const s8b*)(qrow + lg * 8);
        qf[1] = *(const s8b*)(qrow + 32 + lg * 8);
    }

    float m_run[4], l_run[4];
    f4 oacc[4];
#pragma unroll
    for (int i = 0; i < 4; ++i) {
        m_run[i] = -1e30f;
        l_run[i] = 0.f;
        oacc[i]  = (f4){0.f, 0.f, 0.f, 0.f};
    }

    const int srow = t >> 3;    // 0..63
    const int sgg  = t & 7;     // 0..7

    for (int kt = 0; kt < SEQ; kt += 64) {
        __syncthreads();   // previous tile's K/V reads complete

        // ---- stage K and V: one 16B vector copy each per thread ----
        uint4 kg = *(const uint4*)(base + (size_t)(kt + srow) * QKVN + HD + sgg * 8);
        *(uint4*)((char*)Ks + sw_off(srow, sgg * 16)) = kg;
        uint4 vg = *(const uint4*)(vbase + (size_t)srow * SEQ + kt + sgg * 8);
        *(uint4*)((char*)Vt + sw_off(srow, sgg * 16)) = vg;
        __syncthreads();

        // ---- QK^T: S[16 q][64 key] per wave ----
        f4 sacc[4];
#pragma unroll
        for (int nt = 0; nt < 4; ++nt) sacc[nt] = (f4){0.f, 0.f, 0.f, 0.f};
#pragma unroll
        for (int kc = 0; kc < 2; ++kc) {
            const int colb = kc * 64 + lg * 16;
#pragma unroll
            for (int nt = 0; nt < 4; ++nt) {
                s8b kf = *(const s8b*)((const char*)Ks + sw_off(nt * 16 + l15, colb));
                sacc[nt] = __builtin_amdgcn_mfma_f32_16x16x32_bf16(qf[kc], kf, sacc[nt], 0, 0, 0);
            }
        }
        // fold 1/sqrt(HD) * log2(e): softmax runs in exp2 domain
        const float SCL = 0.125f * 1.44269504088896f;
#pragma unroll
        for (int nt = 0; nt < 4; ++nt)
#pragma unroll
            for (int i = 0; i < 4; ++i) sacc[nt][i] *= SCL;

        // ---- online softmax (rows q = lg*4+i, key cols on l15 lanes) ----
        float mt4[4];
#pragma unroll
        for (int i = 0; i < 4; ++i)
            mt4[i] = fmaxf(fmaxf(sacc[0][i], sacc[1][i]), fmaxf(sacc[2][i], sacc[3][i]));
#pragma unroll
        for (int s = 1; s <= 8; s <<= 1)
#pragma unroll
            for (int i = 0; i < 4; ++i)
                mt4[i] = fmaxf(mt4[i], __shfl_xor(mt4[i], s));

        bool grew = (mt4[0] > m_run[0]) | (mt4[1] > m_run[1]) |
                    (mt4[2] > m_run[2]) | (mt4[3] > m_run[3]);
        if (__any(grew)) {
#pragma unroll
            for (int i = 0; i < 4; ++i) {
                const float mn  = fmaxf(m_run[i], mt4[i]);
                const float cor = exp2f(m_run[i] - mn);
                m_run[i] = mn;
                l_run[i] *= cor;
#pragma unroll
                for (int nt = 0; nt < 4; ++nt) oacc[nt][i] *= cor;
            }
        }

        float rs[4] = {0.f, 0.f, 0.f, 0.f};
        const int rowbase = w * 16 + lg * 4;
#pragma unroll
        for (int nt = 0; nt < 4; ++nt) {
#pragma unroll
            for (int i = 0; i < 4; ++i) {
                const float p = exp2f(sacc[nt][i] - m_run[i]);
                rs[i] += p;
                *(unsigned short*)((char*)Ps + sw_off(rowbase + i, (nt * 16 + l15) * 2)) =
                    (unsigned short)f2bf(p);
            }
        }
#pragma unroll
        for (int s = 1; s <= 8; s <<= 1)
#pragma unroll
            for (int i = 0; i < 4; ++i)
                rs[i] += __shfl_xor(rs[i], s);
#pragma unroll
        for (int i = 0; i < 4; ++i) l_run[i] += rs[i];

        // ---- PV: O[16 q][64 d] += P @ V (P rows wave-private) ----
#pragma unroll
        for (int kk = 0; kk < 2; ++kk) {
            const int colb = kk * 64 + lg * 16;
            s8b pf = *(const s8b*)((const char*)Ps + sw_off(w * 16 + l15, colb));
#pragma unroll
            for (int nt = 0; nt < 4; ++nt) {
                s8b vf = *(const s8b*)((const char*)Vt + sw_off(nt * 16 + l15, colb));
                oacc[nt] = __builtin_amdgcn_mfma_f32_16x16x32_bf16(pf, vf, oacc[nt], 0, 0, 0);
            }
        }
    }

    // ---- epilogue: normalize, split into hi/lo bf16 planes [B,S,HID] ----
    float inv[4];
#pragma unroll
    for (int i = 0; i < 4; ++i) inv[i] = 1.f / l_run[i];
#pragma unroll
    for (int i = 0; i < 4; ++i) {
        const size_t rowb = (size_t)(b * SEQ + q0 + w * 16 + lg * 4 + i) * HID + h * HD + l15;
#pragma unroll
        for (int nt = 0; nt < 4; ++nt) {
            const float v = oacc[nt][i] * inv[i];
            const unsigned hu = f2bf(v);
            const unsigned lu = f2bf(v - bf2f(hu));
            att_hi[rowb + nt * 16] = (unsigned short)hu;
            att_lo[rowb + nt * 16] = (unsigned short)lu;
        }
    }
}

// ---------------------------------------------------------------------------
// Workspace layout (exactly 64 MiB — the footprint proven in rounds 0-3):
//   qkv_bf [4096][3072] bf16   24 MiB
//   wh, wl [3072][1024] bf16   2 x 6 MiB
//   owh, owl [1024][1024]      2 x 2 MiB
//   xh, xl [4096][1024]        2 x 8 MiB  (aliased by att_hi/att_lo)
//   vt [32][64][2048] bf16     8 MiB
// ---------------------------------------------------------------------------
extern "C" void kernel_launch(void* const* d_in, const int* in_sizes, int n_in,
                              void* d_out, int out_size, void* d_ws, size_t ws_size,
                              hipStream_t stream) {
    const float* x     = (const float*)d_in[0];
    const float* qkv_w = (const float*)d_in[1];
    const float* qkv_b = (const float*)d_in[2];
    const float* o_w   = (const float*)d_in[3];
    const float* o_b   = (const float*)d_in[4];
    float* out = (float*)d_out;

    char* ws = (char*)d_ws;
    unsigned short* qkv_bf = (unsigned short*)ws;   ws += (size_t)MROWS * QKVN * 2;
    unsigned short* wh     = (unsigned short*)ws;   ws += (size_t)QKVN * HID * 2;
    unsigned short* wl     = (unsigned short*)ws;   ws += (size_t)QKVN * HID * 2;
    unsigned short* owh    = (unsigned short*)ws;   ws += (size_t)HID * HID * 2;
    unsigned short* owl    = (unsigned short*)ws;   ws += (size_t)HID * HID * 2;
    unsigned short* xh     = (unsigned short*)ws;   ws += (size_t)MROWS * HID * 2;
    unsigned short* xl     = (unsigned short*)ws;   ws += (size_t)MROWS * HID * 2;
    unsigned short* vt     = (unsigned short*)ws;
    unsigned short* att_hi = xh;   // alias: x planes dead after QKV GEMM
    unsigned short* att_lo = xl;

    split_hi_lo<<<(MROWS * HID / 8) / 256, 256, 0, stream>>>(x, xh, xl, MROWS * HID / 8);
    split_hi_lo<<<(QKVN * HID / 8) / 256, 256, 0, stream>>>(qkv_w, wh, wl, QKVN * HID / 8);
    split_hi_lo<<<(HID * HID / 8) / 256, 256, 0, stream>>>(o_w, owh, owl, HID * HID / 8);

    gemm_split<1><<<dim3(QKVN / 128, MROWS / 128), 256, 0, stream>>>(
        xh, xl, wh, wl, qkv_b, qkv_bf, QKVN, HID);

    transpose_v<<<dim3(SEQ / 64, BDIM * NH), 256, 0, stream>>>(qkv_bf, vt);

    attn_fwd_mfma<<<dim3(SEQ / QBLK, BDIM * NH), 512, 0, stream>>>(
        qkv_bf, vt, att_hi, att_lo);

    gemm_split<0><<<dim3(HID / 128, MROWS / 128), 256, 0, stream>>>(
        att_hi, att_lo, owh, owl, o_b, out, HID, HID);

    (void)in_sizes; (void)n_in; (void)out_size; (void)ws_size;
}

// Round 8
// 310.973 us; speedup vs baseline: 1.8768x; 1.0260x over previous
//
#include <hip/hip_runtime.h>
#include <hip/hip_bf16.h>

// Problem constants (fixed by the reference)
#define BDIM 2
#define SEQ  2048
#define HID  1024
#define NH   16
#define HD   64
#define MROWS (BDIM * SEQ)   // 4096
#define QKVN  (3 * HID)      // 3072
#define QBLK 128

typedef __attribute__((ext_vector_type(8))) short s8b;   // 8 bf16 (4 VGPRs)
typedef __attribute__((ext_vector_type(4))) float f4;    // MFMA C/D

__device__ __forceinline__ unsigned f2bf(float f) {
    unsigned u = __builtin_bit_cast(unsigned, f);
    return (u + 0x7FFFu + ((u >> 16) & 1u)) >> 16;   // round-to-nearest-even
}
__device__ __forceinline__ float bf2f(unsigned h) {
    return __builtin_bit_cast(float, h << 16);
}
__device__ __forceinline__ unsigned short f2bf_s(float f) {
    return __builtin_bit_cast(unsigned short, __float2bfloat16(f));  // RNE
}

// ---------------------------------------------------------------------------
// Prologue: split fp32 tensor into hi/lo bf16 planes.
// ---------------------------------------------------------------------------
__global__ __launch_bounds__(256) void split_hi_lo(
    const float* __restrict__ src, unsigned short* __restrict__ hi,
    unsigned short* __restrict__ lo, int n8)
{
    const int i = blockIdx.x * 256 + threadIdx.x;
    if (i >= n8) return;
    const float4* s = (const float4*)src + 2 * (size_t)i;
    float4 a = s[0], b = s[1];
    const float v[8] = {a.x, a.y, a.z, a.w, b.x, b.y, b.z, b.w};
    unsigned hu[8], lu[8];
#pragma unroll
    for (int j = 0; j < 8; ++j) {
        hu[j] = f2bf(v[j]);
        lu[j] = f2bf(v[j] - bf2f(hu[j]));
    }
    uint4 hv = {hu[0] | (hu[1] << 16), hu[2] | (hu[3] << 16),
                hu[4] | (hu[5] << 16), hu[6] | (hu[7] << 16)};
    uint4 lv = {lu[0] | (lu[1] << 16), lu[2] | (lu[3] << 16),
                lu[4] | (lu[5] << 16), lu[6] | (lu[7] << 16)};
    *((uint4*)hi + i) = hv;
    *((uint4*)lo + i) = lv;
}

// ---------------------------------------------------------------------------
// Split-bf16 MFMA GEMM (unchanged from round 6/7 — verified good).
// ---------------------------------------------------------------------------
template <int OUTBF>
__global__ __launch_bounds__(256)
__attribute__((amdgpu_waves_per_eu(2, 2)))
void gemm_split(
    const unsigned short* __restrict__ Ah, const unsigned short* __restrict__ Al,
    const unsigned short* __restrict__ Wh, const unsigned short* __restrict__ Wl,
    const float* __restrict__ bias, void* __restrict__ Cout, int N, int K)
{
    const int t   = threadIdx.x;
    const int l   = t & 63;
    const int l15 = t & 15;
    const int lg  = (t >> 4) & 3;
    const int w   = t >> 6;
    const int wr  = w >> 1, wc = w & 1;
    const int bm  = blockIdx.y * 128, bn = blockIdx.x * 128;

    __shared__ unsigned short SB[2][4][128 * 32];

    f4 acc[4][4];
#pragma unroll
    for (int i = 0; i < 4; ++i)
#pragma unroll
        for (int j = 0; j < 4; ++j) acc[i][j] = (f4){0.f, 0.f, 0.f, 0.f};

    const unsigned short* plane_src = (w == 0) ? Ah : (w == 1) ? Al
                                    : (w == 2) ? Wh : Wl;
    const int rb0 = (w < 2) ? bm : bn;
    const int gsw = ((l & 3) ^ ((l >> 2) & 3)) * 8;

    auto stage = [&](int buf, int k0) {
        const unsigned short* gp =
            plane_src + (size_t)(rb0 + (l >> 2)) * K + k0 + gsw;
        unsigned short* lb = &SB[buf][w][0];
#pragma unroll
        for (int c = 0; c < 8; ++c)
            __builtin_amdgcn_global_load_lds(
                (const __attribute__((address_space(1))) void*)(gp + (size_t)(c * 16) * K),
                (__attribute__((address_space(3))) void*)(lb + c * 512),
                16, 0, 0);
    };

    const int ksw = ((lg ^ (l15 & 3)) & 3) << 3;

    stage(0, 0);
    __syncthreads();

    int cur = 0;
    const int nsteps = K >> 5;
    for (int step = 0; step < nsteps; ++step) {
        if (step + 1 < nsteps) stage(cur ^ 1, (step + 1) << 5);

        const unsigned short* base = &SB[cur][0][0];
        s8b bh[4], bl[4];
#pragma unroll
        for (int nt = 0; nt < 4; ++nt) {
            const int ro = (wc * 64 + nt * 16 + l15) * 32 + ksw;
            bh[nt] = *(const s8b*)(base + 2 * 4096 + ro);
            bl[nt] = *(const s8b*)(base + 3 * 4096 + ro);
        }
#pragma unroll
        for (int mt = 0; mt < 4; ++mt) {
            const int ro = (wr * 64 + mt * 16 + l15) * 32 + ksw;
            s8b ah = *(const s8b*)(base + ro);
            s8b al = *(const s8b*)(base + 4096 + ro);
#pragma unroll
            for (int nt = 0; nt < 4; ++nt) {
                acc[mt][nt] = __builtin_amdgcn_mfma_f32_16x16x32_bf16(ah, bh[nt], acc[mt][nt], 0, 0, 0);
                acc[mt][nt] = __builtin_amdgcn_mfma_f32_16x16x32_bf16(ah, bl[nt], acc[mt][nt], 0, 0, 0);
                acc[mt][nt] = __builtin_amdgcn_mfma_f32_16x16x32_bf16(al, bh[nt], acc[mt][nt], 0, 0, 0);
            }
        }
        __syncthreads();
        cur ^= 1;
    }

    float bv[4];
#pragma unroll
    for (int nt = 0; nt < 4; ++nt) bv[nt] = bias[bn + wc * 64 + nt * 16 + l15];

#pragma unroll
    for (int mt = 0; mt < 4; ++mt)
#pragma unroll
        for (int i = 0; i < 4; ++i) {
            const int m = bm + wr * 64 + mt * 16 + lg * 4 + i;
#pragma unroll
            for (int nt = 0; nt < 4; ++nt) {
                const int n = bn + wc * 64 + nt * 16 + l15;
                const float v = acc[mt][nt][i] + bv[nt];
                if (OUTBF)
                    ((unsigned short*)Cout)[(size_t)m * N + n] = (unsigned short)f2bf(v);
                else
                    ((float*)Cout)[(size_t)m * N + n] = v;
            }
        }
}

// ---------------------------------------------------------------------------
// XOR swizzle on 16B granules within a 128B row (LDS tiles).
// ---------------------------------------------------------------------------
__device__ __forceinline__ int sw_off(int row, int colbyte) {
    return row * 128 + (colbyte ^ ((((row & 7) ^ (row >> 3)) & 7) << 4));
}

// ---------------------------------------------------------------------------
// One-shot V pre-transpose: vt[bh][d][s] (unchanged from round 7).
// ---------------------------------------------------------------------------
__global__ __launch_bounds__(256) void transpose_v(
    const unsigned short* __restrict__ qkv, unsigned short* __restrict__ vt)
{
    const int bh = blockIdx.y;
    const int b  = bh >> 4, h = bh & 15;
    const int s0 = blockIdx.x * 64;
    const int t  = threadIdx.x;

    __shared__ unsigned short T[64 * 64];

#pragma unroll
    for (int rep = 0; rep < 2; ++rep) {
        const int idx = t + rep * 256;
        const int srow = idx >> 3, gg = idx & 7;
        uint4 v = *(const uint4*)(qkv + (size_t)(b * SEQ + s0 + srow) * QKVN
                                  + h * (3 * HD) + 2 * HD + gg * 8);
        *(uint4*)((char*)T + sw_off(srow, gg * 16)) = v;
    }
    __syncthreads();
#pragma unroll
    for (int rep = 0; rep < 2; ++rep) {
        const int idx = t + rep * 256;
        const int drow = idx >> 3, gg = idx & 7;
        unsigned short tmp[8];
#pragma unroll
        for (int j = 0; j < 8; ++j)
            tmp[j] = *(const unsigned short*)((const char*)T + sw_off(gg * 8 + j, drow * 2));
        *(uint4*)(vt + ((size_t)bh * 64 + drow) * SEQ + s0 + gg * 8) = *(const uint4*)tmp;
    }
}

// ---------------------------------------------------------------------------
// Flash attention, bf16 MFMA. Round-8 changes:
//  * double-buffered K/V LDS, ONE __syncthreads per 64-key tile; next tile's
//    global loads issued BEFORE compute, ds_writes AFTER (T14 async split)
//  * XCD-aware bijective block swizzle: all 16 q-blocks of 4 heads land on
//    one XCD -> K/V (2 MB) stays L2-resident per XCD
//  * softmax: unscaled domain, p = exp2(fma(s, SCL, -m*SCL)); P conversion
//    via __float2bfloat16; s_setprio(1) around MFMA clusters (T5)
// ---------------------------------------------------------------------------
__global__ __launch_bounds__(512) void attn_fwd_mfma(
    const unsigned short* __restrict__ qkv,
    const unsigned short* __restrict__ vt,
    unsigned short* __restrict__ att_hi, unsigned short* __restrict__ att_lo)
{
    const int t   = threadIdx.x;
    const int w   = t >> 6;     // 0..7
    const int l   = t & 63;
    const int l15 = l & 15;
    const int lg  = l >> 4;

    // Bijective XCD swizzle over the 512-block grid (dispatch id = y*16+x,
    // XCD = id%8 round-robin): XCD c gets bh in {4c..4c+3}, all 16 q-blocks.
    const int id = blockIdx.y * 16 + blockIdx.x;
    const int bh = (id & 7) * 4 + ((id >> 3) & 3);
    const int qx = id >> 5;
    const int b  = bh >> 4;
    const int h  = bh & 15;
    const int q0 = qx * QBLK;

    __shared__ unsigned short Ks[2][64 * 64];  // [buf][key][d], swizzled
    __shared__ unsigned short Vt[2][64 * 64];  // [buf][d][key], swizzled
    __shared__ unsigned short Ps[QBLK * 64];   // [q][key], wave-private rows

    const unsigned short* base  = qkv + (size_t)b * SEQ * QKVN + h * (3 * HD);
    const unsigned short* vbase = vt + (size_t)bh * 64 * SEQ;

    // Q fragments in registers
    s8b qf[2];
    {
        const unsigned short* qrow = base + (size_t)(q0 + w * 16 + l15) * QKVN;
        qf[0] = *(const s8b*)(qrow + lg * 8);
        qf[1] = *(const s8b*)(qrow + 32 + lg * 8);
    }

    float m_run[4], l_run[4];
    f4 oacc[4];
#pragma unroll
    for (int i = 0; i < 4; ++i) {
        m_run[i] = -1e30f;
        l_run[i] = 0.f;
        oacc[i]  = (f4){0.f, 0.f, 0.f, 0.f};
    }

    const int srow = t >> 3;    // 0..63
    const int sgg  = t & 7;     // 0..7
    const int kofs = sw_off(srow, sgg * 16);

    // prologue: stage tile 0 into buf 0
    {
        uint4 kg = *(const uint4*)(base + (size_t)srow * QKVN + HD + sgg * 8);
        uint4 vg = *(const uint4*)(vbase + (size_t)srow * SEQ + sgg * 8);
        *(uint4*)((char*)&Ks[0][0] + kofs) = kg;
        *(uint4*)((char*)&Vt[0][0] + kofs) = vg;
    }
    __syncthreads();

    const float SCL = 0.125f * 1.44269504088896f;   // 1/sqrt(64) * log2(e)
    int cur = 0;

    for (int kt = 0; kt < SEQ; kt += 64) {
        // ---- issue next tile's global loads early (hide under compute) ----
        const bool has_next = (kt + 64 < SEQ);
        uint4 kg, vg;
        if (has_next) {
            kg = *(const uint4*)(base + (size_t)(kt + 64 + srow) * QKVN + HD + sgg * 8);
            vg = *(const uint4*)(vbase + (size_t)srow * SEQ + kt + 64 + sgg * 8);
        }

        // ---- QK^T: S[16 q][64 key] per wave ----
        f4 sacc[4];
#pragma unroll
        for (int nt = 0; nt < 4; ++nt) sacc[nt] = (f4){0.f, 0.f, 0.f, 0.f};
        __builtin_amdgcn_s_setprio(1);
#pragma unroll
        for (int kc = 0; kc < 2; ++kc) {
            const int colb = kc * 64 + lg * 16;
#pragma unroll
            for (int nt = 0; nt < 4; ++nt) {
                s8b kf = *(const s8b*)((const char*)&Ks[cur][0] + sw_off(nt * 16 + l15, colb));
                sacc[nt] = __builtin_amdgcn_mfma_f32_16x16x32_bf16(qf[kc], kf, sacc[nt], 0, 0, 0);
            }
        }
        __builtin_amdgcn_s_setprio(0);

        // ---- online softmax (unscaled domain; exp2 with folded scale) ----
        float mt4[4];
#pragma unroll
        for (int i = 0; i < 4; ++i)
            mt4[i] = fmaxf(fmaxf(sacc[0][i], sacc[1][i]), fmaxf(sacc[2][i], sacc[3][i]));
#pragma unroll
        for (int s = 1; s <= 8; s <<= 1)
#pragma unroll
            for (int i = 0; i < 4; ++i)
                mt4[i] = fmaxf(mt4[i], __shfl_xor(mt4[i], s));

        bool grew = (mt4[0] > m_run[0]) | (mt4[1] > m_run[1]) |
                    (mt4[2] > m_run[2]) | (mt4[3] > m_run[3]);
        if (__any(grew)) {
#pragma unroll
            for (int i = 0; i < 4; ++i) {
                const float mn  = fmaxf(m_run[i], mt4[i]);
                const float cor = exp2f((m_run[i] - mn) * SCL);
                m_run[i] = mn;
                l_run[i] *= cor;
#pragma unroll
                for (int nt = 0; nt < 4; ++nt) oacc[nt][i] *= cor;
            }
        }

        float msc[4], rs[4];
#pragma unroll
        for (int i = 0; i < 4; ++i) { msc[i] = m_run[i] * SCL; rs[i] = 0.f; }

        const int rowbase = w * 16 + lg * 4;
#pragma unroll
        for (int nt = 0; nt < 4; ++nt) {
#pragma unroll
            for (int i = 0; i < 4; ++i) {
                const float p = exp2f(fmaf(sacc[nt][i], SCL, -msc[i]));
                rs[i] += p;
                *(unsigned short*)((char*)Ps + sw_off(rowbase + i, (nt * 16 + l15) * 2)) =
                    f2bf_s(p);
            }
        }
#pragma unroll
        for (int s = 1; s <= 8; s <<= 1)
#pragma unroll
            for (int i = 0; i < 4; ++i)
                rs[i] += __shfl_xor(rs[i], s);
#pragma unroll
        for (int i = 0; i < 4; ++i) l_run[i] += rs[i];

        // ---- PV: O[16 q][64 d] += P @ V (P rows wave-private) ----
        __builtin_amdgcn_s_setprio(1);
#pragma unroll
        for (int kk = 0; kk < 2; ++kk) {
            const int colb = kk * 64 + lg * 16;
            s8b pf = *(const s8b*)((const char*)Ps + sw_off(w * 16 + l15, colb));
#pragma unroll
            for (int nt = 0; nt < 4; ++nt) {
                s8b vf = *(const s8b*)((const char*)&Vt[cur][0] + sw_off(nt * 16 + l15, colb));
                oacc[nt] = __builtin_amdgcn_mfma_f32_16x16x32_bf16(pf, vf, oacc[nt], 0, 0, 0);
            }
        }
        __builtin_amdgcn_s_setprio(0);

        // ---- write next tile into the other buffer, then ONE barrier ----
        if (has_next) {
            *(uint4*)((char*)&Ks[cur ^ 1][0] + kofs) = kg;
            *(uint4*)((char*)&Vt[cur ^ 1][0] + kofs) = vg;
        }
        __syncthreads();
        cur ^= 1;
    }

    // ---- epilogue: normalize, split into hi/lo bf16 planes [B,S,HID] ----
    float inv[4];
#pragma unroll
    for (int i = 0; i < 4; ++i) inv[i] = 1.f / l_run[i];
#pragma unroll
    for (int i = 0; i < 4; ++i) {
        const size_t rowb = (size_t)(b * SEQ + q0 + w * 16 + lg * 4 + i) * HID + h * HD + l15;
#pragma unroll
        for (int nt = 0; nt < 4; ++nt) {
            const float v = oacc[nt][i] * inv[i];
            const unsigned hu = f2bf(v);
            const unsigned lu = f2bf(v - bf2f(hu));
            att_hi[rowb + nt * 16] = (unsigned short)hu;
            att_lo[rowb + nt * 16] = (unsigned short)lu;
        }
    }
}

// ---------------------------------------------------------------------------
// Workspace layout (64 MiB, proven):
//   qkv_bf 24 MiB | wh,wl 2x6 | owh,owl 2x2 | xh,xl 2x8 (aliased att planes)
//   | vt 8 MiB
// ---------------------------------------------------------------------------
extern "C" void kernel_launch(void* const* d_in, const int* in_sizes, int n_in,
                              void* d_out, int out_size, void* d_ws, size_t ws_size,
                              hipStream_t stream) {
    const float* x     = (const float*)d_in[0];
    const float* qkv_w = (const float*)d_in[1];
    const float* qkv_b = (const float*)d_in[2];
    const float* o_w   = (const float*)d_in[3];
    const float* o_b   = (const float*)d_in[4];
    float* out = (float*)d_out;

    char* ws = (char*)d_ws;
    unsigned short* qkv_bf = (unsigned short*)ws;   ws += (size_t)MROWS * QKVN * 2;
    unsigned short* wh     = (unsigned short*)ws;   ws += (size_t)QKVN * HID * 2;
    unsigned short* wl     = (unsigned short*)ws;   ws += (size_t)QKVN * HID * 2;
    unsigned short* owh    = (unsigned short*)ws;   ws += (size_t)HID * HID * 2;
    unsigned short* owl    = (unsigned short*)ws;   ws += (size_t)HID * HID * 2;
    unsigned short* xh     = (unsigned short*)ws;   ws += (size_t)MROWS * HID * 2;
    unsigned short* xl     = (unsigned short*)ws;   ws += (size_t)MROWS * HID * 2;
    unsigned short* vt     = (unsigned short*)ws;
    unsigned short* att_hi = xh;   // alias: x planes dead after QKV GEMM
    unsigned short* att_lo = xl;

    split_hi_lo<<<(MROWS * HID / 8) / 256, 256, 0, stream>>>(x, xh, xl, MROWS * HID / 8);
    split_hi_lo<<<(QKVN * HID / 8) / 256, 256, 0, stream>>>(qkv_w, wh, wl, QKVN * HID / 8);
    split_hi_lo<<<(HID * HID / 8) / 256, 256, 0, stream>>>(o_w, owh, owl, HID * HID / 8);

    gemm_split<1><<<dim3(QKVN / 128, MROWS / 128), 256, 0, stream>>>(
        xh, xl, wh, wl, qkv_b, qkv_bf, QKVN, HID);

    transpose_v<<<dim3(SEQ / 64, BDIM * NH), 256, 0, stream>>>(qkv_bf, vt);

    attn_fwd_mfma<<<dim3(SEQ / QBLK, BDIM * NH), 512, 0, stream>>>(
        qkv_bf, vt, att_hi, att_lo);

    gemm_split<0><<<dim3(HID / 128, MROWS / 128), 256, 0, stream>>>(
        att_hi, att_lo, owh, owl, o_b, out, HID, HID);

    (void)in_sizes; (void)n_in; (void)out_size; (void)ws_size;
}

// Round 9
// 293.814 us; speedup vs baseline: 1.9864x; 1.0584x over previous
//
#include <hip/hip_runtime.h>
#include <hip/hip_bf16.h>

// Problem constants (fixed by the reference)
#define BDIM 2
#define SEQ  2048
#define HID  1024
#define NH   16
#define HD   64
#define MROWS (BDIM * SEQ)   // 4096
#define QKVN  (3 * HID)      // 3072
#define QBLK 128

typedef __attribute__((ext_vector_type(8))) short s8b;   // 8 bf16 (4 VGPRs)
typedef __attribute__((ext_vector_type(4))) float f4;    // MFMA C/D

__device__ __forceinline__ unsigned f2bf(float f) {
    unsigned u = __builtin_bit_cast(unsigned, f);
    return (u + 0x7FFFu + ((u >> 16) & 1u)) >> 16;   // round-to-nearest-even
}
__device__ __forceinline__ float bf2f(unsigned h) {
    return __builtin_bit_cast(float, h << 16);
}

// ---------------------------------------------------------------------------
// Prologue: split fp32 tensor into hi/lo bf16 planes.
// ---------------------------------------------------------------------------
__global__ __launch_bounds__(256) void split_hi_lo(
    const float* __restrict__ src, unsigned short* __restrict__ hi,
    unsigned short* __restrict__ lo, int n8)
{
    const int i = blockIdx.x * 256 + threadIdx.x;
    if (i >= n8) return;
    const float4* s = (const float4*)src + 2 * (size_t)i;
    float4 a = s[0], b = s[1];
    const float v[8] = {a.x, a.y, a.z, a.w, b.x, b.y, b.z, b.w};
    unsigned hu[8], lu[8];
#pragma unroll
    for (int j = 0; j < 8; ++j) {
        hu[j] = f2bf(v[j]);
        lu[j] = f2bf(v[j] - bf2f(hu[j]));
    }
    uint4 hv = {hu[0] | (hu[1] << 16), hu[2] | (hu[3] << 16),
                hu[4] | (hu[5] << 16), hu[6] | (hu[7] << 16)};
    uint4 lv = {lu[0] | (lu[1] << 16), lu[2] | (lu[3] << 16),
                lu[4] | (lu[5] << 16), lu[6] | (lu[7] << 16)};
    *((uint4*)hi + i) = hv;
    *((uint4*)lo + i) = lv;
}

// ---------------------------------------------------------------------------
// Split-bf16 MFMA GEMM (unchanged — verified good since round 6).
// ---------------------------------------------------------------------------
template <int OUTBF>
__global__ __launch_bounds__(256)
__attribute__((amdgpu_waves_per_eu(2, 2)))
void gemm_split(
    const unsigned short* __restrict__ Ah, const unsigned short* __restrict__ Al,
    const unsigned short* __restrict__ Wh, const unsigned short* __restrict__ Wl,
    const float* __restrict__ bias, void* __restrict__ Cout, int N, int K)
{
    const int t   = threadIdx.x;
    const int l   = t & 63;
    const int l15 = t & 15;
    const int lg  = (t >> 4) & 3;
    const int w   = t >> 6;
    const int wr  = w >> 1, wc = w & 1;
    const int bm  = blockIdx.y * 128, bn = blockIdx.x * 128;

    __shared__ unsigned short SB[2][4][128 * 32];

    f4 acc[4][4];
#pragma unroll
    for (int i = 0; i < 4; ++i)
#pragma unroll
        for (int j = 0; j < 4; ++j) acc[i][j] = (f4){0.f, 0.f, 0.f, 0.f};

    const unsigned short* plane_src = (w == 0) ? Ah : (w == 1) ? Al
                                    : (w == 2) ? Wh : Wl;
    const int rb0 = (w < 2) ? bm : bn;
    const int gsw = ((l & 3) ^ ((l >> 2) & 3)) * 8;

    auto stage = [&](int buf, int k0) {
        const unsigned short* gp =
            plane_src + (size_t)(rb0 + (l >> 2)) * K + k0 + gsw;
        unsigned short* lb = &SB[buf][w][0];
#pragma unroll
        for (int c = 0; c < 8; ++c)
            __builtin_amdgcn_global_load_lds(
                (const __attribute__((address_space(1))) void*)(gp + (size_t)(c * 16) * K),
                (__attribute__((address_space(3))) void*)(lb + c * 512),
                16, 0, 0);
    };

    const int ksw = ((lg ^ (l15 & 3)) & 3) << 3;

    stage(0, 0);
    __syncthreads();

    int cur = 0;
    const int nsteps = K >> 5;
    for (int step = 0; step < nsteps; ++step) {
        if (step + 1 < nsteps) stage(cur ^ 1, (step + 1) << 5);

        const unsigned short* base = &SB[cur][0][0];
        s8b bh[4], bl[4];
#pragma unroll
        for (int nt = 0; nt < 4; ++nt) {
            const int ro = (wc * 64 + nt * 16 + l15) * 32 + ksw;
            bh[nt] = *(const s8b*)(base + 2 * 4096 + ro);
            bl[nt] = *(const s8b*)(base + 3 * 4096 + ro);
        }
#pragma unroll
        for (int mt = 0; mt < 4; ++mt) {
            const int ro = (wr * 64 + mt * 16 + l15) * 32 + ksw;
            s8b ah = *(const s8b*)(base + ro);
            s8b al = *(const s8b*)(base + 4096 + ro);
#pragma unroll
            for (int nt = 0; nt < 4; ++nt) {
                acc[mt][nt] = __builtin_amdgcn_mfma_f32_16x16x32_bf16(ah, bh[nt], acc[mt][nt], 0, 0, 0);
                acc[mt][nt] = __builtin_amdgcn_mfma_f32_16x16x32_bf16(ah, bl[nt], acc[mt][nt], 0, 0, 0);
                acc[mt][nt] = __builtin_amdgcn_mfma_f32_16x16x32_bf16(al, bh[nt], acc[mt][nt], 0, 0, 0);
            }
        }
        __syncthreads();
        cur ^= 1;
    }

    float bv[4];
#pragma unroll
    for (int nt = 0; nt < 4; ++nt) bv[nt] = bias[bn + wc * 64 + nt * 16 + l15];

#pragma unroll
    for (int mt = 0; mt < 4; ++mt)
#pragma unroll
        for (int i = 0; i < 4; ++i) {
            const int m = bm + wr * 64 + mt * 16 + lg * 4 + i;
#pragma unroll
            for (int nt = 0; nt < 4; ++nt) {
                const int n = bn + wc * 64 + nt * 16 + l15;
                const float v = acc[mt][nt][i] + bv[nt];
                if (OUTBF)
                    ((unsigned short*)Cout)[(size_t)m * N + n] = (unsigned short)f2bf(v);
                else
                    ((float*)Cout)[(size_t)m * N + n] = v;
            }
        }
}

// ---------------------------------------------------------------------------
// XOR swizzle on 16B granules within a 128B row (LDS tiles).
// ---------------------------------------------------------------------------
__device__ __forceinline__ int sw_off(int row, int colbyte) {
    return row * 128 + (colbyte ^ ((((row & 7) ^ (row >> 3)) & 7) << 4));
}

// ---------------------------------------------------------------------------
// One-shot V pre-transpose: vt[bh][d][s] (unchanged).
// ---------------------------------------------------------------------------
__global__ __launch_bounds__(256) void transpose_v(
    const unsigned short* __restrict__ qkv, unsigned short* __restrict__ vt)
{
    const int bh = blockIdx.y;
    const int b  = bh >> 4, h = bh & 15;
    const int s0 = blockIdx.x * 64;
    const int t  = threadIdx.x;

    __shared__ unsigned short T[64 * 64];

#pragma unroll
    for (int rep = 0; rep < 2; ++rep) {
        const int idx = t + rep * 256;
        const int srow = idx >> 3, gg = idx & 7;
        uint4 v = *(const uint4*)(qkv + (size_t)(b * SEQ + s0 + srow) * QKVN
                                  + h * (3 * HD) + 2 * HD + gg * 8);
        *(uint4*)((char*)T + sw_off(srow, gg * 16)) = v;
    }
    __syncthreads();
#pragma unroll
    for (int rep = 0; rep < 2; ++rep) {
        const int idx = t + rep * 256;
        const int drow = idx >> 3, gg = idx & 7;
        unsigned short tmp[8];
#pragma unroll
        for (int j = 0; j < 8; ++j)
            tmp[j] = *(const unsigned short*)((const char*)T + sw_off(gg * 8 + j, drow * 2));
        *(uint4*)(vt + ((size_t)bh * 64 + drow) * SEQ + s0 + gg * 8) = *(const uint4*)tmp;
    }
}

// ---------------------------------------------------------------------------
// Flash attention, bf16 MFMA. Round-9 changes (VALU-count diet; structure
// identical to round 8):
//  * ALL LDS offsets hoisted out of the K-loop into registers (they are
//    loop-invariant; round-8 asm recomputed sw_off's mul/xor chain per
//    access at VGPR=56). amdgpu_waves_per_eu(4,4) = 128-reg budget = the
//    occupancy the 512-block grid can seat anyway.
//  * l-sum cross-lane reduction DEFERRED to epilogue (per-lane partials;
//    rescale factor is uniform across the row's 16 lanes so partials stay
//    consistent). Removes 16 shfl + 16 add per tile.
//  * staging addresses pointer-bumped.
// ---------------------------------------------------------------------------
__global__ __launch_bounds__(512)
__attribute__((amdgpu_waves_per_eu(4, 4)))
void attn_fwd_mfma(
    const unsigned short* __restrict__ qkv,
    const unsigned short* __restrict__ vt,
    unsigned short* __restrict__ att_hi, unsigned short* __restrict__ att_lo)
{
    const int t   = threadIdx.x;
    const int w   = t >> 6;     // 0..7
    const int l   = t & 63;
    const int l15 = l & 15;
    const int lg  = l >> 4;

    // Bijective XCD swizzle (round 8): XCD c gets bh {4c..4c+3}, all q-blocks.
    const int id = blockIdx.y * 16 + blockIdx.x;
    const int bh = (id & 7) * 4 + ((id >> 3) & 3);
    const int qx = id >> 5;
    const int b  = bh >> 4;
    const int h  = bh & 15;
    const int q0 = qx * QBLK;

    __shared__ unsigned short Ks[2][64 * 64];  // [buf][key][d], swizzled
    __shared__ unsigned short Vt[2][64 * 64];  // [buf][d][key], swizzled
    __shared__ unsigned short Ps[QBLK * 64];   // [q][key], wave-private rows

    const unsigned short* base  = qkv + (size_t)b * SEQ * QKVN + h * (3 * HD);
    const unsigned short* vbase = vt + (size_t)bh * 64 * SEQ;

    // Q fragments in registers
    s8b qf[2];
    {
        const unsigned short* qrow = base + (size_t)(q0 + w * 16 + l15) * QKVN;
        qf[0] = *(const s8b*)(qrow + lg * 8);
        qf[1] = *(const s8b*)(qrow + 32 + lg * 8);
    }

    // ---- hoisted loop-invariant LDS offsets (bytes) ----
    int frag_off[2][4];                  // K and V fragment reads share these
#pragma unroll
    for (int kc = 0; kc < 2; ++kc)
#pragma unroll
        for (int nt = 0; nt < 4; ++nt)
            frag_off[kc][nt] = sw_off(nt * 16 + l15, kc * 64 + lg * 16);
    int pf_off[2];
#pragma unroll
    for (int kk = 0; kk < 2; ++kk)
        pf_off[kk] = sw_off(w * 16 + l15, kk * 64 + lg * 16);
    int pw_off[4][4];                    // Ps writes [nt][i]
    const int rowbase = w * 16 + lg * 4;
#pragma unroll
    for (int nt = 0; nt < 4; ++nt)
#pragma unroll
        for (int i = 0; i < 4; ++i)
            pw_off[nt][i] = sw_off(rowbase + i, (nt * 16 + l15) * 2);

    float m_run[4], l_run[4];
    f4 oacc[4];
#pragma unroll
    for (int i = 0; i < 4; ++i) {
        m_run[i] = -1e30f;
        l_run[i] = 0.f;
        oacc[i]  = (f4){0.f, 0.f, 0.f, 0.f};
    }

    const int srow = t >> 3;    // 0..63
    const int sgg  = t & 7;     // 0..7
    const int kofs = sw_off(srow, sgg * 16);

    // staging pointers (bumped per tile; no per-tile 64-bit mul)
    const unsigned short* kgp = base + (size_t)srow * QKVN + HD + sgg * 8;
    const unsigned short* vgp = vbase + (size_t)srow * SEQ + sgg * 8;

    // prologue: stage tile 0 into buf 0
    {
        uint4 kg = *(const uint4*)kgp;
        uint4 vg = *(const uint4*)vgp;
        *(uint4*)((char*)&Ks[0][0] + kofs) = kg;
        *(uint4*)((char*)&Vt[0][0] + kofs) = vg;
        kgp += (size_t)64 * QKVN;
        vgp += 64;
    }
    __syncthreads();

    const float SCL = 0.125f * 1.44269504088896f;   // 1/sqrt(64) * log2(e)
    int cur = 0;

    for (int kt = 0; kt < SEQ; kt += 64) {
        // ---- issue next tile's global loads early (hide under compute) ----
        const bool has_next = (kt + 64 < SEQ);
        uint4 kg, vg;
        if (has_next) {
            kg = *(const uint4*)kgp;
            vg = *(const uint4*)vgp;
            kgp += (size_t)64 * QKVN;
            vgp += 64;
        }

        // ---- QK^T ----
        f4 sacc[4];
#pragma unroll
        for (int nt = 0; nt < 4; ++nt) sacc[nt] = (f4){0.f, 0.f, 0.f, 0.f};
        __builtin_amdgcn_s_setprio(1);
#pragma unroll
        for (int kc = 0; kc < 2; ++kc) {
#pragma unroll
            for (int nt = 0; nt < 4; ++nt) {
                s8b kf = *(const s8b*)((const char*)&Ks[cur][0] + frag_off[kc][nt]);
                sacc[nt] = __builtin_amdgcn_mfma_f32_16x16x32_bf16(qf[kc], kf, sacc[nt], 0, 0, 0);
            }
        }
        __builtin_amdgcn_s_setprio(0);

        // ---- online softmax ----
        float mt4[4];
#pragma unroll
        for (int i = 0; i < 4; ++i)
            mt4[i] = fmaxf(fmaxf(sacc[0][i], sacc[1][i]), fmaxf(sacc[2][i], sacc[3][i]));
#pragma unroll
        for (int s = 1; s <= 8; s <<= 1)
#pragma unroll
            for (int i = 0; i < 4; ++i)
                mt4[i] = fmaxf(mt4[i], __shfl_xor(mt4[i], s));

        bool grew = (mt4[0] > m_run[0]) | (mt4[1] > m_run[1]) |
                    (mt4[2] > m_run[2]) | (mt4[3] > m_run[3]);
        if (__any(grew)) {
#pragma unroll
            for (int i = 0; i < 4; ++i) {
                const float mn  = fmaxf(m_run[i], mt4[i]);
                const float cor = exp2f((m_run[i] - mn) * SCL);
                m_run[i] = mn;
                l_run[i] *= cor;
#pragma unroll
                for (int nt = 0; nt < 4; ++nt) oacc[nt][i] *= cor;
            }
        }

        float msc[4];
#pragma unroll
        for (int i = 0; i < 4; ++i) msc[i] = m_run[i] * SCL;

#pragma unroll
        for (int nt = 0; nt < 4; ++nt) {
#pragma unroll
            for (int i = 0; i < 4; ++i) {
                const float p = exp2f(fmaf(sacc[nt][i], SCL, -msc[i]));
                l_run[i] += p;    // per-lane partial; reduced in epilogue
                *(unsigned short*)((char*)Ps + pw_off[nt][i]) = (unsigned short)f2bf(p);
            }
        }

        // ---- PV ----
        __builtin_amdgcn_s_setprio(1);
#pragma unroll
        for (int kk = 0; kk < 2; ++kk) {
            s8b pf = *(const s8b*)((const char*)Ps + pf_off[kk]);
#pragma unroll
            for (int nt = 0; nt < 4; ++nt) {
                s8b vf = *(const s8b*)((const char*)&Vt[cur][0] + frag_off[kk][nt]);
                oacc[nt] = __builtin_amdgcn_mfma_f32_16x16x32_bf16(pf, vf, oacc[nt], 0, 0, 0);
            }
        }
        __builtin_amdgcn_s_setprio(0);

        // ---- write next tile into the other buffer, then ONE barrier ----
        if (has_next) {
            *(uint4*)((char*)&Ks[cur ^ 1][0] + kofs) = kg;
            *(uint4*)((char*)&Vt[cur ^ 1][0] + kofs) = vg;
        }
        __syncthreads();
        cur ^= 1;
    }

    // ---- epilogue: one cross-lane l reduction, normalize, split planes ----
#pragma unroll
    for (int s = 1; s <= 8; s <<= 1)
#pragma unroll
        for (int i = 0; i < 4; ++i)
            l_run[i] += __shfl_xor(l_run[i], s);

    float inv[4];
#pragma unroll
    for (int i = 0; i < 4; ++i) inv[i] = 1.f / l_run[i];
#pragma unroll
    for (int i = 0; i < 4; ++i) {
        const size_t rowb = (size_t)(b * SEQ + q0 + w * 16 + lg * 4 + i) * HID + h * HD + l15;
#pragma unroll
        for (int nt = 0; nt < 4; ++nt) {
            const float v = oacc[nt][i] * inv[i];
            const unsigned hu = f2bf(v);
            const unsigned lu = f2bf(v - bf2f(hu));
            att_hi[rowb + nt * 16] = (unsigned short)hu;
            att_lo[rowb + nt * 16] = (unsigned short)lu;
        }
    }
}

// ---------------------------------------------------------------------------
// Workspace layout (64 MiB, proven):
//   qkv_bf 24 MiB | wh,wl 2x6 | owh,owl 2x2 | xh,xl 2x8 (aliased att planes)
//   | vt 8 MiB
// ---------------------------------------------------------------------------
extern "C" void kernel_launch(void* const* d_in, const int* in_sizes, int n_in,
                              void* d_out, int out_size, void* d_ws, size_t ws_size,
                              hipStream_t stream) {
    const float* x     = (const float*)d_in[0];
    const float* qkv_w = (const float*)d_in[1];
    const float* qkv_b = (const float*)d_in[2];
    const float* o_w   = (const float*)d_in[3];
    const float* o_b   = (const float*)d_in[4];
    float* out = (float*)d_out;

    char* ws = (char*)d_ws;
    unsigned short* qkv_bf = (unsigned short*)ws;   ws += (size_t)MROWS * QKVN * 2;
    unsigned short* wh     = (unsigned short*)ws;   ws += (size_t)QKVN * HID * 2;
    unsigned short* wl     = (unsigned short*)ws;   ws += (size_t)QKVN * HID * 2;
    unsigned short* owh    = (unsigned short*)ws;   ws += (size_t)HID * HID * 2;
    unsigned short* owl    = (unsigned short*)ws;   ws += (size_t)HID * HID * 2;
    unsigned short* xh     = (unsigned short*)ws;   ws += (size_t)MROWS * HID * 2;
    unsigned short* xl     = (unsigned short*)ws;   ws += (size_t)MROWS * HID * 2;
    unsigned short* vt     = (unsigned short*)ws;
    unsigned short* att_hi = xh;   // alias: x planes dead after QKV GEMM
    unsigned short* att_lo = xl;

    split_hi_lo<<<(MROWS * HID / 8) / 256, 256, 0, stream>>>(x, xh, xl, MROWS * HID / 8);
    split_hi_lo<<<(QKVN * HID / 8) / 256, 256, 0, stream>>>(qkv_w, wh, wl, QKVN * HID / 8);
    split_hi_lo<<<(HID * HID / 8) / 256, 256, 0, stream>>>(o_w, owh, owl, HID * HID / 8);

    gemm_split<1><<<dim3(QKVN / 128, MROWS / 128), 256, 0, stream>>>(
        xh, xl, wh, wl, qkv_b, qkv_bf, QKVN, HID);

    transpose_v<<<dim3(SEQ / 64, BDIM * NH), 256, 0, stream>>>(qkv_bf, vt);

    attn_fwd_mfma<<<dim3(SEQ / QBLK, BDIM * NH), 512, 0, stream>>>(
        qkv_bf, vt, att_hi, att_lo);

    gemm_split<0><<<dim3(HID / 128, MROWS / 128), 256, 0, stream>>>(
        att_hi, att_lo, owh, owl, o_b, out, HID, HID);

    (void)in_sizes; (void)n_in; (void)out_size; (void)ws_size;
}